// Round 6
// baseline (314.090 us; speedup 1.0000x reference)
//
#include <hip/hip_runtime.h>

// LSTMTrafficPredictor: fused 2-layer LSTM + FC head via MFMA.
// B=2048, T=512, IN=4, H1=64, H2=32, FC=16, OUT=1.
//
// R23 = R22 resubmitted byte-for-byte: Round-5 bench died with
// "MI355X container failed twice" (broker/infra, kernel never ran; no
// counters, no absmax). Kernel audited for container-killers: LDS 9.7KB,
// all LDS offsets bounded (<2048 shorts incl. +64 dup), x reads bounded,
// no hipMalloc/sync in launch (graph-capture safe). Resubmitting unchanged
// to keep the A/B chain vs R21 (263.8us) intact.
//
// R22: swizzle elimination via duplicated batch columns, on R21 (263.8us).
// R21 post-mortem: wave-specialized split won -26%. Step now 618cy/body;
// VALU 59%, MFMA 25%, LDS pipe ~62% (12 waves x 3 ds_read_b128 = 288clk +
// 48 ds_swizzle = 96clk, all bursting post-barrier -> correlated stall).
// R22: the xor-8 ds_swizzle redistribution existed only because batch data
// lived in MFMA cols 0-7 (cols 8-15 zero). Duplicating every z write into
// cols 8-15 (+128B, 2nd ds_write_b16 with offset immediate) makes every
// lane's OWN accumulator valid: col<8 lanes use a0 (tile0), col>=8 use a1
// (tile1). Removes 4 ds_swizzle from BOTH wave types' critical chains
// (MFMA->gates gap) and -96clk/body off the hot LDS pipe for +~12clk of
// off-chain b16 stores. Bit-identical arithmetic. Also: x global-load role
// moved from wave 0 (L1 critical straggler) to wave 8 (L2).
// CLOSED AXES (measured): issue-trimming on the balanced stream (R19 flat),
// VALU x-fold on L1 waves (R20 +23us), multi-block/CU (regs; MB=4 doubles
// wasted MFMA cols), MB=16 (half CUs idle), finer wave split (wave-granular
// issue: masked lanes still cost full trans issue), batch-group phase split
// (quarter-filled MFMA cols double MFMA count).
// Structure: BLK=768 (12 waves: 8 L1 + 4 L2), grid=256, bounds(768,3),
// AGPR-pinned frags, unroll-2 ping-pong, 1 barrier/body, exp2-folded weights.
// k-map (K=128): [h1(0..63) | x(64..67) | 0(68..95) | h2(96..127)]
//   L1: 2 tiles/wave w<8 (unit w*8+nt*4+quad), ks {0,1,2}, C-init=bb1 (AGPR)
//   L2: 2 tiles/wave w>=8 (unit (w-8)*8+tt*4+quad), ks {0,1,3}, C-init=bb2
//   z offset(k,n) = (k>>5)*512 + (((k>>3)&3)*16+n)*8 + (k&7); frag read = lane*8;
//   every write duplicated at n and n+8 (offset +64 shorts = +128 B).
// ACT job map (both layers): lane(quad,col) -> unit base + (col>>3)*4 + quad,
//   batch col&7; col<8 lanes use own acc tile0, col>=8 use own acc tile1.

#define T_LEN 512
#define IN_F  4
#define H1    64
#define H2    32
#define FCN   16
#define MB    8
#define BLK   768
#define NW1   8     // layer-1 waves; waves NW1..11 are layer-2

typedef __attribute__((ext_vector_type(8))) short s8b;  // 8 bf16 = 4 VGPR
typedef __attribute__((ext_vector_type(4))) float f4;   // MFMA acc
typedef __attribute__((ext_vector_type(4))) int   i4;   // 4 dwords (pin unit)

union S8U { s8b v; i4 d; unsigned short u[8]; };
union F4U { f4 v; i4 d; float f[4]; };

// Pin 4 consecutive regs into AGPRs; asm def kills rematerialization.
#define APIN4(x) asm volatile("" : "+a"((x).d))

#define MF(a, b, c) __builtin_amdgcn_mfma_f32_16x16x32_bf16((a), (b), (c), 0, 0, 0)
#define EX2(x) __builtin_amdgcn_exp2f(x)

#define L2E   1.4426950408889634f
#define L2E2  2.885390081777927f   // 2*log2(e)

__device__ __forceinline__ float rcp_(float x) { return __builtin_amdgcn_rcpf(x); }
// tanh(x) via exp2: 1 - 2/(2^(2x*log2e)+1)
__device__ __forceinline__ float tanh_(float x) {
    return 1.0f - 2.0f * rcp_(EX2(x * L2E2) + 1.0f);
}

__device__ __forceinline__ unsigned short bf16_rne(float f) {   // loader only
    unsigned u = __float_as_uint(f);
    u = u + 0x7FFFu + ((u >> 16) & 1u);
    return (unsigned short)(u >> 16);
}
__device__ __forceinline__ unsigned short bf16_cvt(float f) {   // hot path: 1 instr
    unsigned r;
    asm("v_cvt_pk_bf16_f32 %0, %1, %2" : "=v"(r) : "v"(f), "v"(f));
    return (unsigned short)r;
}

// Shared gate math (gates pre-scaled: i,f,o by log2e; g by 2*log2e).
#define GATES_MATH(G_, CREG, HOUT)                                              \
    const float dI = 1.0f + EX2(-(G_)[0]);                                      \
    const float dF = 1.0f + EX2(-(G_)[1]);                                      \
    const float rIF = rcp_(dI * dF);                                            \
    const float I = dF * rIF, F = dI * rIF;                                     \
    const float dG = EX2((G_)[2]) + 1.0f;                                       \
    const float dO = 1.0f + EX2(-(G_)[3]);                                      \
    const float rGO = rcp_(dG * dO);                                            \
    const float Gg = 1.0f - 2.0f * (dO * rGO), O = dG * rGO;                    \
    CREG = fmaf(F, CREG, I * Gg);                                               \
    const float HOUT = O * tanh_(CREG);

// ---- layer-1 body (waves 0..7): 6 MFMA, own-acc select, ACT1, dup h1 store
#define L1_BODY(P, NP)                                                          \
    {                                                                           \
        const s8b z0 = *(const s8b*)(&zz[P][0] + 0 * 512 + offF);               \
        const s8b z1 = *(const s8b*)(&zz[P][0] + 1 * 512 + offF);               \
        const s8b z2 = *(const s8b*)(&zz[P][0] + 2 * 512 + offF);               \
        f4 a0 = MF(wf1[0][0].v, z0, bb1[0].v);                                  \
        f4 a1 = MF(wf1[1][0].v, z0, bb1[1].v);                                  \
        a0 = MF(wf1[0][1].v, z1, a0);                                           \
        a1 = MF(wf1[1][1].v, z1, a1);                                           \
        a0 = MF(wf1[0][2].v, z2, a0);                                           \
        a1 = MF(wf1[1][2].v, z2, a1);                                           \
        f4 g_;                                                                  \
        _Pragma("unroll")                                                       \
        for (int j_ = 0; j_ < 4; ++j_) g_[j_] = lowc ? a0[j_] : a1[j_];         \
        GATES_MATH(g_, c1, h_)                                                  \
        const unsigned short hv = bf16_cvt(h_);                                 \
        zz[NP][offH]      = hv;                                                 \
        zz[NP][offH + 64] = hv;                                                 \
    }

// ---- layer-2 body (waves 8..11): 6 MFMA, own-acc select, ACT2 (lagged),
// dup h2 store; wave 8 also streams x into the NP buffer (dup cols).
#define L2_BODY(P, NP, ACTOK, LDOK)                                             \
    {                                                                           \
        float xn = 0.f;                                                         \
        const bool ld_ = xrole && (LDOK);                                       \
        if (ld_) xn = *xp;                                                      \
        const s8b z0 = *(const s8b*)(&zz[P][0] + 0 * 512 + offF);               \
        const s8b z1 = *(const s8b*)(&zz[P][0] + 1 * 512 + offF);               \
        const s8b z3 = *(const s8b*)(&zz[P][0] + 3 * 512 + offF);               \
        f4 q0 = MF(wf2[0][0].v, z0, bb2[0].v);                                  \
        f4 q1 = MF(wf2[1][0].v, z0, bb2[1].v);                                  \
        q0 = MF(wf2[0][1].v, z1, q0);                                           \
        q1 = MF(wf2[1][1].v, z1, q1);                                           \
        q0 = MF(wf2[0][2].v, z3, q0);                                           \
        q1 = MF(wf2[1][2].v, z3, q1);                                           \
        if (ACTOK) {                                                            \
            f4 g_;                                                              \
            _Pragma("unroll")                                                   \
            for (int j_ = 0; j_ < 4; ++j_) g_[j_] = lowc ? q0[j_] : q1[j_];     \
            GATES_MATH(g_, c2, h_)                                              \
            const unsigned short hv = bf16_cvt(h_);                             \
            zz[NP][off2j]      = hv;                                            \
            zz[NP][off2j + 64] = hv;                                            \
        }                                                                       \
        if (ld_) {                                                              \
            const unsigned short xv = bf16_cvt(xn);                             \
            zz[NP][xoff]      = xv;                                             \
            zz[NP][xoff + 64] = xv;                                             \
        }                                                                       \
        xp += IN_F;                                                             \
    }

__global__ __launch_bounds__(BLK, 3)
void lstm_mfma(const float* __restrict__ x,
               const float* __restrict__ Wih1, const float* __restrict__ Whh1,
               const float* __restrict__ bih1, const float* __restrict__ bhh1,
               const float* __restrict__ Wih2, const float* __restrict__ Whh2,
               const float* __restrict__ bih2, const float* __restrict__ bhh2,
               const float* __restrict__ fc1_w, const float* __restrict__ fc1_b,
               const float* __restrict__ fc2_w, const float* __restrict__ fc2_b,
               float* __restrict__ out)
{
    __shared__ __align__(16) unsigned short zz[2][2048];     // 8 KB
    __shared__ __align__(16) float h2f[MB * H2];
    __shared__ __align__(16) float fcs[MB * FCN];

    const int t    = threadIdx.x;
    const int lane = t & 63;
    const int w    = t >> 6;      // wave 0..11
    const int col  = lane & 15;
    const int quad = lane >> 4;
    const int b0   = blockIdx.x * MB;
    const bool lowc = (col < 8);
    const int w2   = (w >= NW1) ? (w - NW1) : 0;   // L2 wave idx (clamped)

    // ---- weight fragments (bf16, exp2-folded: g-gate rows x 2*log2e) ----
    const float wsc = ((col & 3) == 2) ? L2E2 : L2E;
    S8U wf1[2][3];                // layer1: 2 tiles x ks {0,1,2}
    S8U wf2[2][3];                // layer2: 2 tiles x ks {0,1,3}
    #pragma unroll
    for (int nt = 0; nt < 2; ++nt) {
        const int r1u = (col & 3) * 64 + (w < NW1 ? w : 0) * 8 + nt * 4 + (col >> 2);
        #pragma unroll
        for (int ks = 0; ks < 3; ++ks) {
            #pragma unroll
            for (int j = 0; j < 8; ++j) {
                const int k = ks * 32 + quad * 8 + j;
                float wv = 0.f;
                if      (k < H1)           wv = Whh1[r1u * H1 + k];
                else if (k < H1 + IN_F)    wv = Wih1[r1u * IN_F + (k - H1)];
                wf1[nt][ks].u[j] = bf16_rne(wv * wsc);
            }
        }
    }
    #pragma unroll
    for (int tt = 0; tt < 2; ++tt) {
        const int r2 = (col & 3) * 32 + w2 * 8 + tt * 4 + (col >> 2);
        #pragma unroll
        for (int kf = 0; kf < 3; ++kf) {
            #pragma unroll
            for (int j = 0; j < 8; ++j) {
                const int k = ((kf < 2) ? kf * 32 : 96) + quad * 8 + j;
                const float wv = (k < H1) ? Wih2[r2 * H1 + k]
                                          : Whh2[r2 * H2 + (k - 96)];
                wf2[tt][kf].u[j] = bf16_rne(wv * wsc);
            }
        }
    }
    // biases as exact-f32 MFMA C-init (pre-scaled)
    F4U bb1[2], bb2[2];
    #pragma unroll
    for (int j = 0; j < 4; ++j) {
        const float bsc = (j == 2) ? L2E2 : L2E;
        const int u1a = (w < NW1 ? w : 0) * 8 + quad;         // nt=0 unit
        const int u1b = u1a + 4;                              // nt=1 unit
        bb1[0].f[j] = (bih1[j * 64 + u1a] + bhh1[j * 64 + u1a]) * bsc;
        bb1[1].f[j] = (bih1[j * 64 + u1b] + bhh1[j * 64 + u1b]) * bsc;
        const int u2a = w2 * 8 + quad;                        // tt=0 unit
        const int u2b = u2a + 4;                              // tt=1 unit
        bb2[0].f[j] = (bih2[j * 32 + u2a] + bhh2[j * 32 + u2a]) * bsc;
        bb2[1].f[j] = (bih2[j * 32 + u2b] + bhh2[j * 32 + u2b]) * bsc;
    }

    // ---- PIN fragments + biases into AGPRs ----
    #pragma unroll
    for (int nt = 0; nt < 2; ++nt)
        #pragma unroll
        for (int ks = 0; ks < 3; ++ks) { APIN4(wf1[nt][ks]); APIN4(wf2[nt][ks]); }
    APIN4(bb1[0]); APIN4(bb1[1]); APIN4(bb2[0]); APIN4(bb2[1]);

    // ---- init LDS: zero z (both buffers) ----
    {
        int* pz = (int*)zz;       // 2*2048 shorts = 2048 ints
        for (int i = t; i < 2048; i += BLK) pz[i] = 0;
    }
    __syncthreads();
    if (t < MB * IN_F) {                    // x(0) at k=64+f: off = 1024 + n*8 + f
        const int n = t >> 2, f = t & 3;
        const float xv = x[(size_t)(b0 + n) * T_LEN * IN_F + f];
        const unsigned short xh = bf16_rne(xv);
        zz[0][1024 + n * 8 + f]      = xh;
        zz[0][1024 + n * 8 + f + 64] = xh;   // duplicate into cols 8-15
    }
    float c1 = 0.f;   // L1 job: unit w*8+(col>>3)*4+quad, batch col&7
    float c2 = 0.f;   // L2 job: unit w2*8+(col>>3)*4+quad, batch col&7

    // store offsets
    const int uH    = w * 8 + ((col >> 3) << 2) + quad;            // L1 (w<8)
    const int nH    = col & 7;
    const int offH  = (uH >> 5) * 512 + (((uH >> 3) & 3) * 16 + nH) * 8 + (uH & 7);
    const int u2j   = w2 * 8 + ((col >> 3) << 2) + quad;           // L2 (w>=8)
    const int off2j = 1536 + (((u2j >> 3) & 3) * 16 + nH) * 8 + (u2j & 7);
    const int offF  = lane * 8;                    // frag read base
    // x-stream role: wave 8 (L2), lanes 0..31 — off the L1 critical waves.
    const bool xrole = (w == NW1) && (lane < MB * IN_F);
    const int xn_   = (lane >> 2) & 7, xf_ = lane & 3;
    const int xoff  = 1024 + xn_ * 8 + xf_;
    const float* xp = x + (size_t)(b0 + xn_) * T_LEN * IN_F + IN_F + xf_;  // -> x(1)
    __syncthreads();

    // ================= main recurrence: unrolled x2, 1 barrier/body ==========
    #pragma unroll 1
    for (int s2 = 0; s2 < T_LEN / 2; ++s2) {
        // ---------- body A: s = 2*s2 (read zz[0], write zz[1]) ----------
        if (w < NW1) {
            L1_BODY(0, 1)
        } else {
            L2_BODY(0, 1, (s2 != 0), 1)      // first body: h2(-1) must stay 0
        }
        __syncthreads();
        // ---------- body B: s = 2*s2+1 (read zz[1], write zz[0]) ----------
        if (w < NW1) {
            L1_BODY(1, 0)
        } else {
            L2_BODY(1, 0, 1, (s2 != T_LEN / 2 - 1))
        }
        __syncthreads();
    }

    // ================= epilogue: layer2 step T-1 (zz[0]: h1(511), h2(510)) ====
    if (w >= NW1) {
        const s8b z0 = *(const s8b*)(&zz[0][0] + 0 * 512 + offF);
        const s8b z1 = *(const s8b*)(&zz[0][0] + 1 * 512 + offF);
        const s8b z3 = *(const s8b*)(&zz[0][0] + 3 * 512 + offF);
        f4 q0 = MF(wf2[0][0].v, z0, bb2[0].v);
        f4 q1 = MF(wf2[1][0].v, z0, bb2[1].v);
        q0 = MF(wf2[0][1].v, z1, q0);
        q1 = MF(wf2[1][1].v, z1, q1);
        q0 = MF(wf2[0][2].v, z3, q0);
        q1 = MF(wf2[1][2].v, z3, q1);
        f4 g_;
        #pragma unroll
        for (int j_ = 0; j_ < 4; ++j_) g_[j_] = lowc ? q0[j_] : q1[j_];
        GATES_MATH(g_, c2, h_)
        h2f[nH * H2 + u2j] = h_;
    }
    __syncthreads();

    // ================= FC head =================
    if (t < MB * FCN) {
        const int b = t >> 4, j = t & 15;
        float s1 = fc1_b[j];
        #pragma unroll
        for (int k = 0; k < H2; ++k)
            s1 = fmaf(fc1_w[j * H2 + k], h2f[b * H2 + k], s1);
        fcs[b * FCN + j] = fmaxf(s1, 0.f);
    }
    __syncthreads();
    if (t < MB) {
        float s2v = fc2_b[0];
        #pragma unroll
        for (int j = 0; j < FCN; ++j)
            s2v = fmaf(fc2_w[j], fcs[t * FCN + j], s2v);
        out[b0 + t] = s2v;
    }
}

extern "C" void kernel_launch(void* const* d_in, const int* in_sizes, int n_in,
                              void* d_out, int out_size, void* d_ws, size_t ws_size,
                              hipStream_t stream) {
    const float* x     = (const float*)d_in[0];
    const float* Wih1  = (const float*)d_in[1];
    const float* Whh1  = (const float*)d_in[2];
    const float* bih1  = (const float*)d_in[3];
    const float* bhh1  = (const float*)d_in[4];
    const float* Wih2  = (const float*)d_in[5];
    const float* Whh2  = (const float*)d_in[6];
    const float* bih2  = (const float*)d_in[7];
    const float* bhh2  = (const float*)d_in[8];
    const float* fc1_w = (const float*)d_in[9];
    const float* fc1_b = (const float*)d_in[10];
    const float* fc2_w = (const float*)d_in[11];
    const float* fc2_b = (const float*)d_in[12];
    float* out = (float*)d_out;

    const int n_batch = 2048;
    dim3 grid(n_batch / MB), block(BLK);
    lstm_mfma<<<grid, block, 0, stream>>>(x, Wih1, Whh1, bih1, bhh1,
                                          Wih2, Whh2, bih2, bhh2,
                                          fc1_w, fc1_b, fc2_w, fc2_b, out);
}